// Round 6
// baseline (581.311 us; speedup 1.0000x reference)
//
#include <hip/hip_runtime.h>
#include <hip/hip_bf16.h>
#include <stdint.h>

#define B_ 2
#define S_ 2048
#define DIM_ 2048
#define H_ 16
#define M_ (B_*S_)          // 4096 rows

typedef __bf16 bf16x8 __attribute__((ext_vector_type(8)));
typedef float f32x4 __attribute__((ext_vector_type(4)));
typedef __hip_bfloat16 bf16;

// ---------------------------------------------------------------- helpers
__device__ __forceinline__ void async_copy16(const bf16* gsrc, bf16* ldst) {
  __builtin_amdgcn_global_load_lds((const __attribute__((address_space(1))) uint32_t*)gsrc,
                                   (__attribute__((address_space(3))) uint32_t*)ldst, 16, 0, 0);
}

// ---------------------------------------------------------------- fp32 -> bf16 convert
__global__ void cvt_bf16_kernel(const float* __restrict__ in, bf16* __restrict__ out, int n) {
  int i = (blockIdx.x * 256 + threadIdx.x) * 4;
  if (i >= n) return;
  float4 v = *(const float4*)(in + i);
  bf16 o[4] = {__float2bfloat16(v.x), __float2bfloat16(v.y),
               __float2bfloat16(v.z), __float2bfloat16(v.w)};
  *(ushort4*)(out + i) = *(ushort4*)o;
}

// ---------------------------------------------------------------- W[K][N] f32 -> Wt[N][K] bf16
__global__ void transpose_cvt_kernel(const float* __restrict__ W, bf16* __restrict__ Wt,
                                     int K, int N) {
  __shared__ float tile[32][33];
  int n0 = blockIdx.x * 32;
  int k0 = blockIdx.y * 32;
  int tx = threadIdx.x, ty = threadIdx.y;
  #pragma unroll
  for (int i = 0; i < 4; i++)
    tile[ty + i*8][tx] = W[(size_t)(k0 + ty + i*8) * N + n0 + tx];
  __syncthreads();
  #pragma unroll
  for (int i = 0; i < 4; i++)
    Wt[(size_t)(n0 + ty + i*8) * K + k0 + tx] = __float2bfloat16(tile[tx][ty + i*8]);
}

// ---------------------------------------------------------------- GEMM: C = A[M][K] @ Bt[N][K]^T + bias, fused epilogues
// m97 structure: 128x128 tile, BK=32, 4 waves, global_load_lds width 16.
// T1: XCD-aware bijective block swizzle (all launches have nwg % 8 == 0).
// MODE 0: fp32 row-major out.
// MODE 6 (q-proj || kv-proj, A=xb, N=4608):
//   cols    0..3071: q -> Qa[bh][s][192], RoPE on d>=128, * softmax scale (C=Qa, bias)
//   cols 3072..4095: k_rope (flat 2048+cc) -> Ka with RoPE (C2=Ka, bias2[cc])
//   cols 4096..4607: c (pre-LN) -> C3=c_raw[M][512] (bias2[cc])
// MODE 7 (k_nope || v-proj, A=cn, N=4096):
//   cols    0..2047: k_nope -> Ka flat 0..2047 with RoPE on d>=128 (C=Ka, bias)
//   cols 2048..4095: v -> Vt[bh][dv][S_] fused transpose (C2=Vt, bias2[cc])
// Fusion invariants (audited): all path boundaries (3072, 4096, 2048) are
// multiples of 128 -> block-uniform; head starts (h*192[-2048]) and rope
// starts (h*192+128[-2048]) are multiples of 16 -> lane-uniform per 16-col
// tile; rope pairs are adjacent cols -> partner via __shfl_xor(val,1) with
// all 64 lanes active. All flat<2048 rope positions are heads 0..9 (head 10's
// rope starts exactly at flat 2048), so MODE 7 + MODE 6 cover all of Ka.
template <typename OutT, int MODE>
__global__ void __launch_bounds__(256) gemm_bt_kernel(
    const bf16* __restrict__ A, const bf16* __restrict__ Bt,
    const float* __restrict__ bias, const float* __restrict__ bias2,
    OutT* __restrict__ C, bf16* __restrict__ C2, bf16* __restrict__ C3,
    int M, int N, int K,
    const float* __restrict__ cosT, const float* __restrict__ sinT) {
  __shared__ bf16 As[128 * 32];
  __shared__ bf16 Bs[128 * 32];
  const int tid = threadIdx.x;
  const int wid = tid >> 6;
  const int lane = tid & 63;
  const int g = lane >> 4;
  const int c = lane & 15;

  // XCD swizzle
  int bx = blockIdx.x, by = blockIdx.y;
  {
    int gx = gridDim.x;
    int nwg = gx * gridDim.y;
    if ((nwg & 7) == 0) {
      int flat = by * gx + bx;
      int swz = (flat & 7) * (nwg >> 3) + (flat >> 3);
      bx = swz % gx;
      by = swz / gx;
    }
  }
  const int row0 = by * 128;
  const int col0 = bx * 128;
  const int wr = (wid >> 1) * 64;
  const int wc = (wid & 1) * 64;

  f32x4 acc[4][4] = {};

  const int srow = wid * 32 + (lane >> 2);
  const int scol = (lane & 3) * 8;
  const bf16* ga0 = A  + (size_t)(row0 + srow) * K + scol;
  const bf16* gb0 = Bt + (size_t)(col0 + srow) * K + scol;
  bf16* la0 = &As[(wid * 32) * 32];
  bf16* la1 = &As[(wid * 32 + 16) * 32];
  bf16* lb0 = &Bs[(wid * 32) * 32];
  bf16* lb1 = &Bs[(wid * 32 + 16) * 32];

  for (int k0 = 0; k0 < K; k0 += 32) {
    async_copy16(ga0 + k0, la0);
    async_copy16(ga0 + (size_t)16 * K + k0, la1);
    async_copy16(gb0 + k0, lb0);
    async_copy16(gb0 + (size_t)16 * K + k0, lb1);
    __syncthreads();
    bf16x8 af[4], bfr[4];
    #pragma unroll
    for (int i = 0; i < 4; i++) {
      af[i]  = *(const bf16x8*)&As[(wr + i*16 + c) * 32 + g*8];
      bfr[i] = *(const bf16x8*)&Bs[(wc + i*16 + c) * 32 + g*8];
    }
    #pragma unroll
    for (int mi = 0; mi < 4; mi++)
      #pragma unroll
      for (int ni = 0; ni < 4; ni++)
        acc[mi][ni] = __builtin_amdgcn_mfma_f32_16x16x32_bf16(af[mi], bfr[ni], acc[mi][ni], 0, 0, 0);
    __syncthreads();
  }

  if constexpr (MODE == 0) {
    #pragma unroll
    for (int mi = 0; mi < 4; mi++) {
      int row = row0 + wr + mi*16 + g*4;
      #pragma unroll
      for (int ni = 0; ni < 4; ni++) {
        int col = col0 + wc + ni*16 + c;
        float bv = bias[col];
        #pragma unroll
        for (int r = 0; r < 4; r++)
          C[(size_t)(row + r) * N + col] = acc[mi][ni][r] + bv;
      }
    }
  } else {
    // helper lambdas shared by MODE 6 / MODE 7 epilogues
    auto rope_write = [&](bf16* __restrict__ dst, size_t obase, int s, int d,
                          float val[4], float scale) {
      if (d >= 128) {                 // lane-uniform per 16-col tile
        const int pp = (d - 128) >> 1;
        const bool even = (c & 1) == 0;
        #pragma unroll
        for (int r = 0; r < 4; r++) {
          float partner = __shfl_xor(val[r], 1);
          float a  = even ? val[r] : partner;
          float bb = even ? partner : val[r];
          float ct = cosT[(s + r) * 32 + pp], st = sinT[(s + r) * 32 + pp];
          float o = even ? (a * ct - bb * st) : (a * st + bb * ct);
          dst[obase + (size_t)r * 192] = __float2bfloat16(o * scale);
        }
      } else {
        #pragma unroll
        for (int r = 0; r < 4; r++)
          dst[obase + (size_t)r * 192] = __float2bfloat16(val[r] * scale);
      }
    };

    #pragma unroll
    for (int mi = 0; mi < 4; mi++) {
      int row = row0 + wr + mi*16 + g*4;
      int s = row & (S_ - 1);
      int b = row >> 11;
      #pragma unroll
      for (int ni = 0; ni < 4; ni++) {
        int col = col0 + wc + ni*16 + c;
        float val[4];
        if constexpr (MODE == 6) {
          if (col < 3072) {           // ---- q path (block-uniform)
            float bv = bias[col];
            #pragma unroll
            for (int r = 0; r < 4; r++) val[r] = acc[mi][ni][r] + bv;
            int h = col / 192;
            int d = col - h * 192;
            size_t obase = ((size_t)(b * H_ + h) * S_ + s) * 192 + d;
            rope_write((bf16*)C, obase, s, d, val, 0.07216878364870323f);  // 192^-0.5
          } else {
            int cc = col - 3072;      // kv cols 0..1535
            float bv = bias2[cc];
            #pragma unroll
            for (int r = 0; r < 4; r++) val[r] = acc[mi][ni][r] + bv;
            if (cc < 1024) {          // ---- k_rope -> Ka flat 2048+cc
              int flat = 2048 + cc;
              int h = flat / 192;     // 10..15
              int d = flat - h * 192;
              size_t obase = ((size_t)(b * H_ + h) * S_ + s) * 192 + d;
              rope_write(C2, obase, s, d, val, 1.0f);
            } else {                  // ---- c (pre-layernorm) -> c_raw [M][512]
              #pragma unroll
              for (int r = 0; r < 4; r++)
                C3[(size_t)(row + r) * 512 + (cc - 1024)] = __float2bfloat16(val[r]);
            }
          }
        } else {  // MODE 7
          if (col < 2048) {           // ---- k_nope -> Ka flat 0..2047
            float bv = bias[col];
            #pragma unroll
            for (int r = 0; r < 4; r++) val[r] = acc[mi][ni][r] + bv;
            int h = col / 192;        // 0..10
            int d = col - h * 192;
            size_t obase = ((size_t)(b * H_ + h) * S_ + s) * 192 + d;
            rope_write((bf16*)C, obase, s, d, val, 1.0f);
          } else {                    // ---- v -> Vt[bh][dv][S_] fused transpose
            int cc = col - 2048;      // 0..2047 = h*128+dv
            float bv = bias2[cc];
            bf16 tmp[4];
            #pragma unroll
            for (int r = 0; r < 4; r++) tmp[r] = __float2bfloat16(acc[mi][ni][r] + bv);
            size_t idx = ((size_t)(b * H_ + (cc >> 7)) * 128 + (cc & 127)) * S_ + s;
            *(ushort4*)&C2[idx] = *(ushort4*)tmp;
          }
        }
      }
    }
  }
}

// ---------------------------------------------------------------- layernorm of c_raw [M][512] -> cn [M][512]
// 256 threads = 4 rows x 64 lanes; wave-level reduction per row.
__global__ void __launch_bounds__(256) layernorm_kernel(
    const bf16* __restrict__ craw,
    const float* __restrict__ gamma, const float* __restrict__ beta,
    bf16* __restrict__ cn) {
  int row = blockIdx.x * 4 + (threadIdx.x >> 6);
  int lane = threadIdx.x & 63;
  bf16x8 v = *(const bf16x8*)(craw + (size_t)row * 512 + lane * 8);
  float f[8], sum = 0.f, sq = 0.f;
  #pragma unroll
  for (int j = 0; j < 8; j++) { f[j] = (float)v[j]; sum += f[j]; sq += f[j]*f[j]; }
  #pragma unroll
  for (int d = 1; d < 64; d <<= 1) {
    sum += __shfl_xor(sum, d);
    sq  += __shfl_xor(sq, d);
  }
  float mu = sum * (1.f/512.f);
  float var = sq * (1.f/512.f) - mu*mu;
  float rstd = rsqrtf(var + 1e-5f);
  bf16x8 ov;
  #pragma unroll
  for (int j = 0; j < 8; j++) {
    int col = lane*8 + j;
    float o = (f[j] - mu) * rstd * gamma[col] + beta[col];
    ov[j] = (__bf16)o;
  }
  *(bf16x8*)(cn + (size_t)row * 512 + lane * 8) = ov;
}

// ---------------------------------------------------------------- causal flash attention
// Qa,Ka [BH][S][192] (q pre-scaled), Vt [BH][128][S] -> Oa [b,s,h,128]
// 4 waves x 16 q-rows; KBLK=64; swapped QK^T so softmax is lane-local + 2 shfl.
// qt reversed so heavy (large-qt) blocks launch first (causal load imbalance).
__global__ void __launch_bounds__(256) flash_attn_kernel(
    const bf16* __restrict__ Qa, const bf16* __restrict__ Ka,
    const bf16* __restrict__ Vt, bf16* __restrict__ Oa) {
  __shared__ bf16 Ks[64 * 200];    // K tile, padded stride 200
  __shared__ bf16 Vs[128 * 72];    // V^T tile, padded stride 72
  __shared__ bf16 Ps[4][16 * 72];  // per-wave P [q][kv], padded
  const int tid = threadIdx.x;
  const int wid = tid >> 6, lane = tid & 63;
  const int g = lane >> 4, c = lane & 15;
  const int bh = blockIdx.y;
  const int qt = gridDim.x - 1 - blockIdx.x;
  const int q0 = qt * 64;
  const int qw = q0 + wid * 16;
  const float NEG_INF = -__builtin_inff();

  bf16x8 qf[6];
  {
    const bf16* qrow = Qa + ((size_t)bh * S_ + qw + c) * 192;
    #pragma unroll
    for (int t = 0; t < 6; t++) qf[t] = *(const bf16x8*)(qrow + t*32 + g*8);
  }
  float m = NEG_INF, lsum = 0.f;
  f32x4 o[8] = {};

  const int kr = tid >> 2, kpart = tid & 3;
  const int vdv = tid >> 1, vhalf = tid & 1;

  for (int kt = 0; kt <= qt; kt++) {
    const int kv0 = kt * 64;
    {
      const bf16* src = Ka + ((size_t)bh * S_ + kv0 + kr) * 192;
      #pragma unroll
      for (int j = 0; j < 6; j++) {
        int col = (kpart + 4*j) * 8;
        *(bf16x8*)&Ks[kr * 200 + col] = *(const bf16x8*)(src + col);
      }
      const bf16* vsrc = Vt + ((size_t)bh * 128 + vdv) * S_ + kv0;
      #pragma unroll
      for (int j = 0; j < 4; j++) {
        int col = (vhalf*4 + j) * 8;
        *(bf16x8*)&Vs[vdv * 72 + col] = *(const bf16x8*)(vsrc + col);
      }
    }
    __syncthreads();

    // S^T[kv][q] = K . Q^T  (swapped)
    f32x4 sc[4] = {};
    #pragma unroll
    for (int mb = 0; mb < 4; mb++) {
      #pragma unroll
      for (int t = 0; t < 6; t++) {
        bf16x8 kf = *(const bf16x8*)&Ks[(mb*16 + c) * 200 + t*32 + g*8];
        sc[mb] = __builtin_amdgcn_mfma_f32_16x16x32_bf16(kf, qf[t], sc[mb], 0, 0, 0);
      }
    }
    if (kt == qt) {
      #pragma unroll
      for (int mb = 0; mb < 4; mb++)
        #pragma unroll
        for (int r = 0; r < 4; r++)
          if (kv0 + mb*16 + g*4 + r > qw + c) sc[mb][r] = NEG_INF;
    }
    // online softmax for q = qw + c
    float pm = NEG_INF;
    #pragma unroll
    for (int mb = 0; mb < 4; mb++)
      #pragma unroll
      for (int r = 0; r < 4; r++) pm = fmaxf(pm, sc[mb][r]);
    pm = fmaxf(pm, __shfl_xor(pm, 16));
    pm = fmaxf(pm, __shfl_xor(pm, 32));
    const float newm = fmaxf(m, pm);
    const float alpha = __expf(m - newm);   // 0 on first tile
    float rs = 0.f;
    float pv[4][4];
    #pragma unroll
    for (int mb = 0; mb < 4; mb++)
      #pragma unroll
      for (int r = 0; r < 4; r++) { pv[mb][r] = __expf(sc[mb][r] - newm); rs += pv[mb][r]; }
    rs += __shfl_xor(rs, 16);
    rs += __shfl_xor(rs, 32);
    lsum = lsum * alpha + rs;
    m = newm;
    // P -> LDS [q=c][kv], bf16
    #pragma unroll
    for (int mb = 0; mb < 4; mb++) {
      bf16 w[4];
      #pragma unroll
      for (int r = 0; r < 4; r++) w[r] = __float2bfloat16(pv[mb][r]);
      *(ushort4*)&Ps[wid][c * 72 + mb*16 + g*4] = *(ushort4*)w;
    }
    __syncthreads();
    // rescale O (rows q = qw + 4g + r) by alpha of that row
    float ar[4];
    #pragma unroll
    for (int r = 0; r < 4; r++) ar[r] = __shfl(alpha, 20*g + r);
    #pragma unroll
    for (int nb = 0; nb < 8; nb++)
      #pragma unroll
      for (int r = 0; r < 4; r++) o[nb][r] *= ar[r];
    // O += P @ V
    #pragma unroll
    for (int t2 = 0; t2 < 2; t2++) {
      bf16x8 pa = *(const bf16x8*)&Ps[wid][c * 72 + t2*32 + g*8];
      #pragma unroll
      for (int nb = 0; nb < 8; nb++) {
        bf16x8 vf = *(const bf16x8*)&Vs[(nb*16 + c) * 72 + t2*32 + g*8];
        o[nb] = __builtin_amdgcn_mfma_f32_16x16x32_bf16(pa, vf, o[nb], 0, 0, 0);
      }
    }
    __syncthreads();
  }

  float lr[4];
  #pragma unroll
  for (int r = 0; r < 4; r++) lr[r] = 1.f / __shfl(lsum, 20*g + r);
  const int b = bh >> 4, h = bh & 15;
  #pragma unroll
  for (int nb = 0; nb < 8; nb++) {
    #pragma unroll
    for (int r = 0; r < 4; r++) {
      int srow = qw + g*4 + r;
      int dv = nb*16 + c;
      Oa[(((size_t)(b * S_ + srow)) * H_ + h) * 128 + dv] = __float2bfloat16(o[nb][r] * lr[r]);
    }
  }
}

// ---------------------------------------------------------------- launch
extern "C" void kernel_launch(void* const* d_in, const int* in_sizes, int n_in,
                              void* d_out, int out_size, void* d_ws, size_t ws_size,
                              hipStream_t stream) {
  const float* x     = (const float*)d_in[0];
  const float* wq_w  = (const float*)d_in[1];
  const float* wq_b  = (const float*)d_in[2];
  const float* wkv_w = (const float*)d_in[3];
  const float* wkv_b = (const float*)d_in[4];
  const float* kvn_g = (const float*)d_in[5];
  const float* kvn_b = (const float*)d_in[6];
  const float* wk_w  = (const float*)d_in[7];
  const float* wk_b  = (const float*)d_in[8];
  const float* wv_w  = (const float*)d_in[9];
  const float* wv_b  = (const float*)d_in[10];
  const float* wo_w  = (const float*)d_in[11];
  const float* wo_b  = (const float*)d_in[12];
  const float* cosT  = (const float*)d_in[13];
  const float* sinT  = (const float*)d_in[14];
  float* out = (float*)d_out;
  (void)in_sizes; (void)n_in; (void)out_size; (void)ws_size;

  char* p = (char*)d_ws;
  auto alloc = [&](size_t elems) { bf16* r = (bf16*)p; p += elems * 2; return r; };
  bf16* xb      = alloc((size_t)M_ * 2048);
  bf16* wqkv_t  = alloc((size_t)4608 * 2048);   // [wq_t (3072) | wkv_t (1536)] rows
  bf16* wkv2_t  = alloc((size_t)4096 * 512);    // [wk_t (2048) | wv_t (2048)] rows
  bf16* wo_t    = alloc((size_t)2048 * 2048);
  bf16* c_raw   = alloc((size_t)M_ * 512);
  bf16* cn      = alloc((size_t)M_ * 512);
  bf16* q_at    = alloc((size_t)M_ * 3072);
  bf16* k_at    = alloc((size_t)M_ * 3072);
  bf16* v_at    = alloc((size_t)M_ * 2048);
  bf16* att_o   = alloc((size_t)M_ * 2048);

  // x -> bf16
  cvt_bf16_kernel<<<dim3((M_*2048)/1024), 256, 0, stream>>>(x, xb, M_*2048);
  // weight transposes into concatenated buffers
  transpose_cvt_kernel<<<dim3(3072/32, 2048/32), dim3(32,8), 0, stream>>>(wq_w,  wqkv_t,                      2048, 3072);
  transpose_cvt_kernel<<<dim3(1536/32, 2048/32), dim3(32,8), 0, stream>>>(wkv_w, wqkv_t + (size_t)3072*2048, 2048, 1536);
  transpose_cvt_kernel<<<dim3(2048/32, 512/32),  dim3(32,8), 0, stream>>>(wk_w,  wkv2_t,                     512,  2048);
  transpose_cvt_kernel<<<dim3(2048/32, 512/32),  dim3(32,8), 0, stream>>>(wv_w,  wkv2_t + (size_t)2048*512,  512,  2048);
  transpose_cvt_kernel<<<dim3(2048/32, 2048/32), dim3(32,8), 0, stream>>>(wo_w,  wo_t,                       2048, 2048);
  // merged q-proj || kv-proj: Qa (RoPE+scale), Ka flat 2048.. (k_rope+RoPE), c_raw
  gemm_bt_kernel<bf16,6><<<dim3(4608/128, M_/128), 256, 0, stream>>>(
      xb, wqkv_t, wq_b, wkv_b, q_at, k_at, c_raw, M_, 4608, 2048, cosT, sinT);
  // layernorm on c
  layernorm_kernel<<<dim3(M_/4), 256, 0, stream>>>(c_raw, kvn_g, kvn_b, cn);
  // merged k_nope || v-proj: Ka flat 0..2047 (RoPE), Vt fused transpose
  gemm_bt_kernel<bf16,7><<<dim3(4096/128, M_/128), 256, 0, stream>>>(
      cn, wkv2_t, wk_b, wv_b, k_at, v_at, nullptr, M_, 4096, 512, cosT, sinT);
  // flash attention
  flash_attn_kernel<<<dim3(S_/64, B_*H_), 256, 0, stream>>>(q_at, k_at, v_at, att_o);
  // out = attn @ wo + wo_b  (fp32 out)
  gemm_bt_kernel<float,0><<<dim3(2048/128, M_/128), 256, 0, stream>>>(
      att_o, wo_t, wo_b, nullptr, out, nullptr, nullptr, M_, 2048, 2048, nullptr, nullptr);
}

// Round 7
// 537.993 us; speedup vs baseline: 1.0805x; 1.0805x over previous
//
#include <hip/hip_runtime.h>
#include <hip/hip_bf16.h>
#include <stdint.h>

#define B_ 2
#define S_ 2048
#define DIM_ 2048
#define H_ 16
#define M_ (B_*S_)          // 4096 rows

typedef __bf16 bf16x8 __attribute__((ext_vector_type(8)));
typedef float f32x4 __attribute__((ext_vector_type(4)));
typedef __hip_bfloat16 bf16;

// ---------------------------------------------------------------- helpers
__device__ __forceinline__ void async_copy16(const bf16* gsrc, bf16* ldst) {
  __builtin_amdgcn_global_load_lds((const __attribute__((address_space(1))) uint32_t*)gsrc,
                                   (__attribute__((address_space(3))) uint32_t*)ldst, 16, 0, 0);
}

// ---------------------------------------------------------------- fp32 -> bf16 convert
__global__ void cvt_bf16_kernel(const float* __restrict__ in, bf16* __restrict__ out, int n) {
  int i = (blockIdx.x * 256 + threadIdx.x) * 4;
  if (i >= n) return;
  float4 v = *(const float4*)(in + i);
  bf16 o[4] = {__float2bfloat16(v.x), __float2bfloat16(v.y),
               __float2bfloat16(v.z), __float2bfloat16(v.w)};
  *(ushort4*)(out + i) = *(ushort4*)o;
}

// ---------------------------------------------------------------- W[K][N] f32 -> Wt[N][K] bf16
__global__ void transpose_cvt_kernel(const float* __restrict__ W, bf16* __restrict__ Wt,
                                     int K, int N) {
  __shared__ float tile[32][33];
  int n0 = blockIdx.x * 32;
  int k0 = blockIdx.y * 32;
  int tx = threadIdx.x, ty = threadIdx.y;
  #pragma unroll
  for (int i = 0; i < 4; i++)
    tile[ty + i*8][tx] = W[(size_t)(k0 + ty + i*8) * N + n0 + tx];
  __syncthreads();
  #pragma unroll
  for (int i = 0; i < 4; i++)
    Wt[(size_t)(n0 + ty + i*8) * K + k0 + tx] = __float2bfloat16(tile[tx][ty + i*8]);
}

// ---------------------------------------------------------------- GEMM: C = A[M][K] @ Bt[N][K]^T + bias, fused epilogues
// m97 structure: 128x128 tile, BK=32, 4 waves, global_load_lds width 16.
// T1: XCD-aware bijective block swizzle (all launches have nwg % 8 == 0).
// MODE 0: fp32 row-major out.
// MODE 6 (q-proj || kv-proj, A=xb, N=4608):
//   cols    0..3071: q -> Qa[bh][s][192], RoPE on d>=128, * softmax scale (C=Qa, bias)
//   cols 3072..4095: k_rope (flat 2048+cc) -> Ka with RoPE (C2=Ka, bias2[cc])
//   cols 4096..4607: c (pre-LN) -> C3=c_raw[M][512] (bias2[cc])
// MODE 7 (k_nope || v-proj, A=cn, N=4096):
//   cols    0..2047: k_nope -> Ka flat 0..2047 with RoPE on d>=128 (C=Ka, bias)
//   cols 2048..4095: v -> Vt[bh][dv][S_] fused transpose (C2=Vt, bias2[cc])
// Fusion invariants (audited): all path boundaries (3072, 4096, 2048) are
// multiples of 128 -> block-uniform; head starts (h*192[-2048]) and rope
// starts (h*192+128[-2048]) are multiples of 16 -> lane-uniform per 16-col
// tile; rope pairs are adjacent cols -> partner via __shfl_xor(val,1) with
// all 64 lanes active. All flat<2048 rope positions are heads 0..9 (head 10's
// rope starts exactly at flat 2048), so MODE 7 + MODE 6 cover all of Ka.
template <typename OutT, int MODE>
__global__ void __launch_bounds__(256) gemm_bt_kernel(
    const bf16* __restrict__ A, const bf16* __restrict__ Bt,
    const float* __restrict__ bias, const float* __restrict__ bias2,
    OutT* __restrict__ C, bf16* __restrict__ C2, bf16* __restrict__ C3,
    int M, int N, int K,
    const float* __restrict__ cosT, const float* __restrict__ sinT) {
  __shared__ bf16 As[128 * 32];
  __shared__ bf16 Bs[128 * 32];
  const int tid = threadIdx.x;
  const int wid = tid >> 6;
  const int lane = tid & 63;
  const int g = lane >> 4;
  const int c = lane & 15;

  // XCD swizzle
  int bx = blockIdx.x, by = blockIdx.y;
  {
    int gx = gridDim.x;
    int nwg = gx * gridDim.y;
    if ((nwg & 7) == 0) {
      int flat = by * gx + bx;
      int swz = (flat & 7) * (nwg >> 3) + (flat >> 3);
      bx = swz % gx;
      by = swz / gx;
    }
  }
  const int row0 = by * 128;
  const int col0 = bx * 128;
  const int wr = (wid >> 1) * 64;
  const int wc = (wid & 1) * 64;

  f32x4 acc[4][4] = {};

  const int srow = wid * 32 + (lane >> 2);
  const int scol = (lane & 3) * 8;
  const bf16* ga0 = A  + (size_t)(row0 + srow) * K + scol;
  const bf16* gb0 = Bt + (size_t)(col0 + srow) * K + scol;
  bf16* la0 = &As[(wid * 32) * 32];
  bf16* la1 = &As[(wid * 32 + 16) * 32];
  bf16* lb0 = &Bs[(wid * 32) * 32];
  bf16* lb1 = &Bs[(wid * 32 + 16) * 32];

  for (int k0 = 0; k0 < K; k0 += 32) {
    async_copy16(ga0 + k0, la0);
    async_copy16(ga0 + (size_t)16 * K + k0, la1);
    async_copy16(gb0 + k0, lb0);
    async_copy16(gb0 + (size_t)16 * K + k0, lb1);
    __syncthreads();
    bf16x8 af[4], bfr[4];
    #pragma unroll
    for (int i = 0; i < 4; i++) {
      af[i]  = *(const bf16x8*)&As[(wr + i*16 + c) * 32 + g*8];
      bfr[i] = *(const bf16x8*)&Bs[(wc + i*16 + c) * 32 + g*8];
    }
    #pragma unroll
    for (int mi = 0; mi < 4; mi++)
      #pragma unroll
      for (int ni = 0; ni < 4; ni++)
        acc[mi][ni] = __builtin_amdgcn_mfma_f32_16x16x32_bf16(af[mi], bfr[ni], acc[mi][ni], 0, 0, 0);
    __syncthreads();
  }

  if constexpr (MODE == 0) {
    #pragma unroll
    for (int mi = 0; mi < 4; mi++) {
      int row = row0 + wr + mi*16 + g*4;
      #pragma unroll
      for (int ni = 0; ni < 4; ni++) {
        int col = col0 + wc + ni*16 + c;
        float bv = bias[col];
        #pragma unroll
        for (int r = 0; r < 4; r++)
          C[(size_t)(row + r) * N + col] = acc[mi][ni][r] + bv;
      }
    }
  } else {
    // helper lambdas shared by MODE 6 / MODE 7 epilogues
    auto rope_write = [&](bf16* __restrict__ dst, size_t obase, int s, int d,
                          float val[4], float scale) {
      if (d >= 128) {                 // lane-uniform per 16-col tile
        const int pp = (d - 128) >> 1;
        const bool even = (c & 1) == 0;
        #pragma unroll
        for (int r = 0; r < 4; r++) {
          float partner = __shfl_xor(val[r], 1);
          float a  = even ? val[r] : partner;
          float bb = even ? partner : val[r];
          float ct = cosT[(s + r) * 32 + pp], st = sinT[(s + r) * 32 + pp];
          float o = even ? (a * ct - bb * st) : (a * st + bb * ct);
          dst[obase + (size_t)r * 192] = __float2bfloat16(o * scale);
        }
      } else {
        #pragma unroll
        for (int r = 0; r < 4; r++)
          dst[obase + (size_t)r * 192] = __float2bfloat16(val[r] * scale);
      }
    };

    #pragma unroll
    for (int mi = 0; mi < 4; mi++) {
      int row = row0 + wr + mi*16 + g*4;
      int s = row & (S_ - 1);
      int b = row >> 11;
      #pragma unroll
      for (int ni = 0; ni < 4; ni++) {
        int col = col0 + wc + ni*16 + c;
        float val[4];
        if constexpr (MODE == 6) {
          if (col < 3072) {           // ---- q path (block-uniform)
            float bv = bias[col];
            #pragma unroll
            for (int r = 0; r < 4; r++) val[r] = acc[mi][ni][r] + bv;
            int h = col / 192;
            int d = col - h * 192;
            size_t obase = ((size_t)(b * H_ + h) * S_ + s) * 192 + d;
            rope_write((bf16*)C, obase, s, d, val, 0.07216878364870323f);  // 192^-0.5
          } else {
            int cc = col - 3072;      // kv cols 0..1535
            float bv = bias2[cc];
            #pragma unroll
            for (int r = 0; r < 4; r++) val[r] = acc[mi][ni][r] + bv;
            if (cc < 1024) {          // ---- k_rope -> Ka flat 2048+cc
              int flat = 2048 + cc;
              int h = flat / 192;     // 10..15
              int d = flat - h * 192;
              size_t obase = ((size_t)(b * H_ + h) * S_ + s) * 192 + d;
              rope_write(C2, obase, s, d, val, 1.0f);
            } else {                  // ---- c (pre-layernorm) -> c_raw [M][512]
              #pragma unroll
              for (int r = 0; r < 4; r++)
                C3[(size_t)(row + r) * 512 + (cc - 1024)] = __float2bfloat16(val[r]);
            }
          }
        } else {  // MODE 7
          if (col < 2048) {           // ---- k_nope -> Ka flat 0..2047
            float bv = bias[col];
            #pragma unroll
            for (int r = 0; r < 4; r++) val[r] = acc[mi][ni][r] + bv;
            int h = col / 192;        // 0..10
            int d = col - h * 192;
            size_t obase = ((size_t)(b * H_ + h) * S_ + s) * 192 + d;
            rope_write((bf16*)C, obase, s, d, val, 1.0f);
          } else {                    // ---- v -> Vt[bh][dv][S_] fused transpose
            int cc = col - 2048;      // 0..2047 = h*128+dv
            float bv = bias2[cc];
            bf16 tmp[4];
            #pragma unroll
            for (int r = 0; r < 4; r++) tmp[r] = __float2bfloat16(acc[mi][ni][r] + bv);
            size_t idx = ((size_t)(b * H_ + (cc >> 7)) * 128 + (cc & 127)) * S_ + s;
            *(ushort4*)&C2[idx] = *(ushort4*)tmp;
          }
        }
      }
    }
  }
}

// ---------------------------------------------------------------- layernorm of c_raw [M][512] -> cn [M][512]
// 256 threads = 4 rows x 64 lanes; wave-level reduction per row.
__global__ void __launch_bounds__(256) layernorm_kernel(
    const bf16* __restrict__ craw,
    const float* __restrict__ gamma, const float* __restrict__ beta,
    bf16* __restrict__ cn) {
  int row = blockIdx.x * 4 + (threadIdx.x >> 6);
  int lane = threadIdx.x & 63;
  bf16x8 v = *(const bf16x8*)(craw + (size_t)row * 512 + lane * 8);
  float f[8], sum = 0.f, sq = 0.f;
  #pragma unroll
  for (int j = 0; j < 8; j++) { f[j] = (float)v[j]; sum += f[j]; sq += f[j]*f[j]; }
  #pragma unroll
  for (int d = 1; d < 64; d <<= 1) {
    sum += __shfl_xor(sum, d);
    sq  += __shfl_xor(sq, d);
  }
  float mu = sum * (1.f/512.f);
  float var = sq * (1.f/512.f) - mu*mu;
  float rstd = rsqrtf(var + 1e-5f);
  bf16x8 ov;
  #pragma unroll
  for (int j = 0; j < 8; j++) {
    int col = lane*8 + j;
    float o = (f[j] - mu) * rstd * gamma[col] + beta[col];
    ov[j] = (__bf16)o;
  }
  *(bf16x8*)(cn + (size_t)row * 512 + lane * 8) = ov;
}

// ---------------------------------------------------------------- causal flash attention v2
// Qa,Ka [BH][S][192] (q pre-scaled), Vt [BH][128][S] -> Oa [b,s,h,128]
// 128 q-rows/block, 4 waves x 32 q (two 16-row groups) -> each K/V LDS read
// serves 2x the FLOPs (was LDS-throughput-bound at 16 FLOP/B; now 32).
// T14 async-STAGE: next tile's K/V global loads issue into registers before
// current tile's compute; regs -> LDS after the post-compute barrier.
// qt reversed so heavy (large-qt) blocks launch first (causal imbalance).
__global__ void __launch_bounds__(256, 2) flash_attn_kernel(
    const bf16* __restrict__ Qa, const bf16* __restrict__ Ka,
    const bf16* __restrict__ Vt, bf16* __restrict__ Oa) {
  __shared__ bf16 Ks[64 * 200];     // K tile, padded stride 200 (conflict-free b128)
  __shared__ bf16 Vs[128 * 72];     // V^T tile, padded stride 72
  __shared__ bf16 Ps[4][32 * 72];   // per-wave P [q 32][kv 64], padded
  const int tid = threadIdx.x;
  const int wid = tid >> 6, lane = tid & 63;
  const int g = lane >> 4, c = lane & 15;
  const int bh = blockIdx.y;
  const int qt = gridDim.x - 1 - blockIdx.x;   // 0..15
  const int q0 = qt * 128;
  const int qw = q0 + wid * 32;                // wave's 32 q-rows
  const float NEG_INF = -__builtin_inff();

  // Q fragments for both 16-row groups (stay in registers for whole kernel)
  bf16x8 qf[2][6];
  #pragma unroll
  for (int rg = 0; rg < 2; rg++) {
    const bf16* qrow = Qa + ((size_t)bh * S_ + qw + rg*16 + c) * 192;
    #pragma unroll
    for (int t = 0; t < 6; t++) qf[rg][t] = *(const bf16x8*)(qrow + t*32 + g*8);
  }
  float m[2] = {NEG_INF, NEG_INF}, lsum[2] = {0.f, 0.f};
  f32x4 o[2][8] = {};

  const int kr = tid >> 2, kpart = tid & 3;    // K staging: row 0..63, col-chunk
  const int vdv = tid >> 1, vhalf = tid & 1;   // V staging: dv 0..127, half

  bf16x8 kst[6], vst[4];                       // staged regs (next tile)
  const int nkt = 2*qt + 2;                    // tiles 0..2qt+1 cover rows q0..q0+127

  auto load_regs = [&](int kt) {
    const bf16* src = Ka + ((size_t)bh * S_ + kt*64 + kr) * 192;
    #pragma unroll
    for (int j = 0; j < 6; j++) kst[j] = *(const bf16x8*)(src + (kpart + 4*j) * 8);
    const bf16* vsrc = Vt + ((size_t)bh * 128 + vdv) * S_ + kt*64;
    #pragma unroll
    for (int j = 0; j < 4; j++) vst[j] = *(const bf16x8*)(vsrc + (vhalf*4 + j) * 8);
  };
  auto write_lds = [&]() {
    #pragma unroll
    for (int j = 0; j < 6; j++) *(bf16x8*)&Ks[kr * 200 + (kpart + 4*j) * 8] = kst[j];
    #pragma unroll
    for (int j = 0; j < 4; j++) *(bf16x8*)&Vs[vdv * 72 + (vhalf*4 + j) * 8] = vst[j];
  };

  load_regs(0);
  write_lds();
  __syncthreads();

  for (int kt = 0; kt < nkt; kt++) {
    const int kv0 = kt * 64;
    if (kt + 1 < nkt) load_regs(kt + 1);   // prefetch next tile into regs (T14)

    #pragma unroll
    for (int rg = 0; rg < 2; rg++) {
      const int qbase = qw + rg * 16;      // this group's first q-row
      if (kv0 > qbase + 15) continue;      // fully masked for this group (wave-uniform)

      // S^T[kv][q] = K . Q^T  (swapped)
      f32x4 sc[4] = {};
      #pragma unroll
      for (int mb = 0; mb < 4; mb++) {
        #pragma unroll
        for (int t = 0; t < 6; t++) {
          bf16x8 kf = *(const bf16x8*)&Ks[(mb*16 + c) * 200 + t*32 + g*8];
          sc[mb] = __builtin_amdgcn_mfma_f32_16x16x32_bf16(kf, qf[rg][t], sc[mb], 0, 0, 0);
        }
      }
      if (kv0 + 63 > qbase) {              // causal mask needed (wave-uniform)
        #pragma unroll
        for (int mb = 0; mb < 4; mb++)
          #pragma unroll
          for (int r = 0; r < 4; r++)
            if (kv0 + mb*16 + g*4 + r > qbase + c) sc[mb][r] = NEG_INF;
      }
      // online softmax for q = qbase + c
      float pm = NEG_INF;
      #pragma unroll
      for (int mb = 0; mb < 4; mb++)
        #pragma unroll
        for (int r = 0; r < 4; r++) pm = fmaxf(pm, sc[mb][r]);
      pm = fmaxf(pm, __shfl_xor(pm, 16));
      pm = fmaxf(pm, __shfl_xor(pm, 32));
      const float newm = fmaxf(m[rg], pm);
      const float alpha = __expf(m[rg] - newm);   // 0 on first live tile
      float rs = 0.f;
      float pv[4][4];
      #pragma unroll
      for (int mb = 0; mb < 4; mb++)
        #pragma unroll
        for (int r = 0; r < 4; r++) { pv[mb][r] = __expf(sc[mb][r] - newm); rs += pv[mb][r]; }
      rs += __shfl_xor(rs, 16);
      rs += __shfl_xor(rs, 32);
      lsum[rg] = lsum[rg] * alpha + rs;
      m[rg] = newm;
      // P -> LDS [q=rg*16+c][kv], bf16 (wave-private region)
      #pragma unroll
      for (int mb = 0; mb < 4; mb++) {
        bf16 w[4];
        #pragma unroll
        for (int r = 0; r < 4; r++) w[r] = __float2bfloat16(pv[mb][r]);
        *(ushort4*)&Ps[wid][(rg*16 + c) * 72 + mb*16 + g*4] = *(ushort4*)w;
      }
      // rescale O (rows q = qbase + 4g + r) by that row's alpha
      float ar[4];
      #pragma unroll
      for (int r = 0; r < 4; r++) ar[r] = __shfl(alpha, 20*g + r);
      #pragma unroll
      for (int nb = 0; nb < 8; nb++)
        #pragma unroll
        for (int r = 0; r < 4; r++) o[rg][nb][r] *= ar[r];
      // O += P @ V
      #pragma unroll
      for (int t2 = 0; t2 < 2; t2++) {
        bf16x8 pa = *(const bf16x8*)&Ps[wid][(rg*16 + c) * 72 + t2*32 + g*8];
        #pragma unroll
        for (int nb = 0; nb < 8; nb++) {
          bf16x8 vf = *(const bf16x8*)&Vs[(nb*16 + c) * 72 + t2*32 + g*8];
          o[rg][nb] = __builtin_amdgcn_mfma_f32_16x16x32_bf16(pa, vf, o[rg][nb], 0, 0, 0);
        }
      }
    }

    if (kt + 1 < nkt) {
      __syncthreads();     // all waves done reading tile kt
      write_lds();         // staged regs -> LDS (vmcnt wait auto-inserted)
      __syncthreads();     // tile kt+1 ready
    }
  }

  const int b = bh >> 4, h = bh & 15;
  #pragma unroll
  for (int rg = 0; rg < 2; rg++) {
    float lr[4];
    #pragma unroll
    for (int r = 0; r < 4; r++) lr[r] = 1.f / __shfl(lsum[rg], 20*g + r);
    #pragma unroll
    for (int nb = 0; nb < 8; nb++) {
      #pragma unroll
      for (int r = 0; r < 4; r++) {
        int srow = qw + rg*16 + g*4 + r;
        int dv = nb*16 + c;
        Oa[(((size_t)(b * S_ + srow)) * H_ + h) * 128 + dv] = __float2bfloat16(o[rg][nb][r] * lr[r]);
      }
    }
  }
}

// ---------------------------------------------------------------- launch
extern "C" void kernel_launch(void* const* d_in, const int* in_sizes, int n_in,
                              void* d_out, int out_size, void* d_ws, size_t ws_size,
                              hipStream_t stream) {
  const float* x     = (const float*)d_in[0];
  const float* wq_w  = (const float*)d_in[1];
  const float* wq_b  = (const float*)d_in[2];
  const float* wkv_w = (const float*)d_in[3];
  const float* wkv_b = (const float*)d_in[4];
  const float* kvn_g = (const float*)d_in[5];
  const float* kvn_b = (const float*)d_in[6];
  const float* wk_w  = (const float*)d_in[7];
  const float* wk_b  = (const float*)d_in[8];
  const float* wv_w  = (const float*)d_in[9];
  const float* wv_b  = (const float*)d_in[10];
  const float* wo_w  = (const float*)d_in[11];
  const float* wo_b  = (const float*)d_in[12];
  const float* cosT  = (const float*)d_in[13];
  const float* sinT  = (const float*)d_in[14];
  float* out = (float*)d_out;
  (void)in_sizes; (void)n_in; (void)out_size; (void)ws_size;

  char* p = (char*)d_ws;
  auto alloc = [&](size_t elems) { bf16* r = (bf16*)p; p += elems * 2; return r; };
  bf16* xb      = alloc((size_t)M_ * 2048);
  bf16* wqkv_t  = alloc((size_t)4608 * 2048);   // [wq_t (3072) | wkv_t (1536)] rows
  bf16* wkv2_t  = alloc((size_t)4096 * 512);    // [wk_t (2048) | wv_t (2048)] rows
  bf16* wo_t    = alloc((size_t)2048 * 2048);
  bf16* c_raw   = alloc((size_t)M_ * 512);
  bf16* cn      = alloc((size_t)M_ * 512);
  bf16* q_at    = alloc((size_t)M_ * 3072);
  bf16* k_at    = alloc((size_t)M_ * 3072);
  bf16* v_at    = alloc((size_t)M_ * 2048);
  bf16* att_o   = alloc((size_t)M_ * 2048);

  // x -> bf16
  cvt_bf16_kernel<<<dim3((M_*2048)/1024), 256, 0, stream>>>(x, xb, M_*2048);
  // weight transposes into concatenated buffers
  transpose_cvt_kernel<<<dim3(3072/32, 2048/32), dim3(32,8), 0, stream>>>(wq_w,  wqkv_t,                      2048, 3072);
  transpose_cvt_kernel<<<dim3(1536/32, 2048/32), dim3(32,8), 0, stream>>>(wkv_w, wqkv_t + (size_t)3072*2048, 2048, 1536);
  transpose_cvt_kernel<<<dim3(2048/32, 512/32),  dim3(32,8), 0, stream>>>(wk_w,  wkv2_t,                     512,  2048);
  transpose_cvt_kernel<<<dim3(2048/32, 512/32),  dim3(32,8), 0, stream>>>(wv_w,  wkv2_t + (size_t)2048*512,  512,  2048);
  transpose_cvt_kernel<<<dim3(2048/32, 2048/32), dim3(32,8), 0, stream>>>(wo_w,  wo_t,                       2048, 2048);
  // merged q-proj || kv-proj: Qa (RoPE+scale), Ka flat 2048.. (k_rope+RoPE), c_raw
  gemm_bt_kernel<bf16,6><<<dim3(4608/128, M_/128), 256, 0, stream>>>(
      xb, wqkv_t, wq_b, wkv_b, q_at, k_at, c_raw, M_, 4608, 2048, cosT, sinT);
  // layernorm on c
  layernorm_kernel<<<dim3(M_/4), 256, 0, stream>>>(c_raw, kvn_g, kvn_b, cn);
  // merged k_nope || v-proj: Ka flat 0..2047 (RoPE), Vt fused transpose
  gemm_bt_kernel<bf16,7><<<dim3(4096/128, M_/128), 256, 0, stream>>>(
      cn, wkv2_t, wk_b, wv_b, k_at, v_at, nullptr, M_, 4096, 512, cosT, sinT);
  // flash attention (128 q-rows/block, reg-prefetch double-stage)
  flash_attn_kernel<<<dim3(S_/128, B_*H_), 256, 0, stream>>>(q_at, k_at, v_at, att_o);
  // out = attn @ wo + wo_b  (fp32 out)
  gemm_bt_kernel<float,0><<<dim3(2048/128, M_/128), 256, 0, stream>>>(
      att_o, wo_t, wo_b, nullptr, out, nullptr, nullptr, M_, 2048, 2048, nullptr, nullptr);
}

// Round 8
// 527.085 us; speedup vs baseline: 1.1029x; 1.0207x over previous
//
#include <hip/hip_runtime.h>
#include <hip/hip_bf16.h>
#include <stdint.h>

#define B_ 2
#define S_ 2048
#define DIM_ 2048
#define H_ 16
#define M_ (B_*S_)          // 4096 rows

typedef __bf16 bf16x8 __attribute__((ext_vector_type(8)));
typedef float f32x4 __attribute__((ext_vector_type(4)));
typedef __hip_bfloat16 bf16;

// ---------------------------------------------------------------- helpers
__device__ __forceinline__ void async_copy16(const bf16* gsrc, bf16* ldst) {
  __builtin_amdgcn_global_load_lds((const __attribute__((address_space(1))) uint32_t*)gsrc,
                                   (__attribute__((address_space(3))) uint32_t*)ldst, 16, 0, 0);
}

// ---------------------------------------------------------------- fp32 -> bf16 convert
__global__ void cvt_bf16_kernel(const float* __restrict__ in, bf16* __restrict__ out, int n) {
  int i = (blockIdx.x * 256 + threadIdx.x) * 4;
  if (i >= n) return;
  float4 v = *(const float4*)(in + i);
  bf16 o[4] = {__float2bfloat16(v.x), __float2bfloat16(v.y),
               __float2bfloat16(v.z), __float2bfloat16(v.w)};
  *(ushort4*)(out + i) = *(ushort4*)o;
}

// ---------------------------------------------------------------- W[K][N] f32 -> Wt[N][K] bf16
__global__ void transpose_cvt_kernel(const float* __restrict__ W, bf16* __restrict__ Wt,
                                     int K, int N) {
  __shared__ float tile[32][33];
  int n0 = blockIdx.x * 32;
  int k0 = blockIdx.y * 32;
  int tx = threadIdx.x, ty = threadIdx.y;
  #pragma unroll
  for (int i = 0; i < 4; i++)
    tile[ty + i*8][tx] = W[(size_t)(k0 + ty + i*8) * N + n0 + tx];
  __syncthreads();
  #pragma unroll
  for (int i = 0; i < 4; i++)
    Wt[(size_t)(n0 + ty + i*8) * K + k0 + tx] = __float2bfloat16(tile[tx][ty + i*8]);
}

// ---------------------------------------------------------------- GEMM: C = A[M][K] @ Bt[N][K]^T + bias, fused epilogues
// m97 structure: 128x128 tile, BK=32, 4 waves, global_load_lds width 16,
// + T3 minimum-2-phase: double-buffered LDS, stage(t+1) issued BEFORE
// compute(t) so fetch latency hides under MFMA; one barrier per K-step
// (__syncthreads drains vmcnt+lgkmcnt -> race-free by construction).
// T1: XCD-aware bijective block swizzle (all launches have nwg % 8 == 0).
// MODE 0: fp32 row-major out.
// MODE 6 (q-proj || kv-proj, A=xb, N=4608):
//   cols    0..3071: q -> Qa[bh][s][192], RoPE on d>=128, * softmax scale (C=Qa, bias)
//   cols 3072..4095: k_rope (flat 2048+cc) -> Ka with RoPE (C2=Ka, bias2[cc])
//   cols 4096..4607: c (pre-LN) -> C3=c_raw[M][512] (bias2[cc])
// MODE 7 (k_nope || v-proj, A=cn, N=4096):
//   cols    0..2047: k_nope -> Ka flat 0..2047 with RoPE on d>=128 (C=Ka, bias)
//   cols 2048..4095: v -> Vt[bh][dv][S_] fused transpose (C2=Vt, bias2[cc])
// Fusion invariants (audited): all path boundaries (3072, 4096, 2048) are
// multiples of 128 -> block-uniform; head starts (h*192[-2048]) and rope
// starts (h*192+128[-2048]) are multiples of 16 -> lane-uniform per 16-col
// tile; rope pairs are adjacent cols -> partner via __shfl_xor(val,1) with
// all 64 lanes active. All flat<2048 rope positions are heads 0..9 (head 10's
// rope starts exactly at flat 2048), so MODE 7 + MODE 6 cover all of Ka.
template <typename OutT, int MODE>
__global__ void __launch_bounds__(256) gemm_bt_kernel(
    const bf16* __restrict__ A, const bf16* __restrict__ Bt,
    const float* __restrict__ bias, const float* __restrict__ bias2,
    OutT* __restrict__ C, bf16* __restrict__ C2, bf16* __restrict__ C3,
    int M, int N, int K,
    const float* __restrict__ cosT, const float* __restrict__ sinT) {
  __shared__ bf16 As[2][128 * 32];
  __shared__ bf16 Bs[2][128 * 32];
  const int tid = threadIdx.x;
  const int wid = tid >> 6;
  const int lane = tid & 63;
  const int g = lane >> 4;
  const int c = lane & 15;

  // XCD swizzle
  int bx = blockIdx.x, by = blockIdx.y;
  {
    int gx = gridDim.x;
    int nwg = gx * gridDim.y;
    if ((nwg & 7) == 0) {
      int flat = by * gx + bx;
      int swz = (flat & 7) * (nwg >> 3) + (flat >> 3);
      bx = swz % gx;
      by = swz / gx;
    }
  }
  const int row0 = by * 128;
  const int col0 = bx * 128;
  const int wr = (wid >> 1) * 64;
  const int wc = (wid & 1) * 64;

  f32x4 acc[4][4] = {};

  const int srow = wid * 32 + (lane >> 2);
  const int scol = (lane & 3) * 8;
  const bf16* ga0 = A  + (size_t)(row0 + srow) * K + scol;
  const bf16* gb0 = Bt + (size_t)(col0 + srow) * K + scol;
  const int lofs0 = (wid * 32) * 32;
  const int lofs1 = (wid * 32 + 16) * 32;

  auto stage = [&](int t, int buf) {
    int k0 = t * 32;
    async_copy16(ga0 + k0, &As[buf][lofs0]);
    async_copy16(ga0 + (size_t)16 * K + k0, &As[buf][lofs1]);
    async_copy16(gb0 + k0, &Bs[buf][lofs0]);
    async_copy16(gb0 + (size_t)16 * K + k0, &Bs[buf][lofs1]);
  };

  const int nt = K >> 5;
  stage(0, 0);
  __syncthreads();            // drains vmcnt(0): tile 0 resident
  int cur = 0;
  for (int t = 0; t < nt; t++) {
    if (t + 1 < nt) stage(t + 1, cur ^ 1);   // async, hides under MFMA below
    bf16x8 af[4], bfr[4];
    #pragma unroll
    for (int i = 0; i < 4; i++) {
      af[i]  = *(const bf16x8*)&As[cur][(wr + i*16 + c) * 32 + g*8];
      bfr[i] = *(const bf16x8*)&Bs[cur][(wc + i*16 + c) * 32 + g*8];
    }
    #pragma unroll
    for (int mi = 0; mi < 4; mi++)
      #pragma unroll
      for (int ni = 0; ni < 4; ni++)
        acc[mi][ni] = __builtin_amdgcn_mfma_f32_16x16x32_bf16(af[mi], bfr[ni], acc[mi][ni], 0, 0, 0);
    __syncthreads();          // drains vmcnt (next tile landed) + lgkmcnt
    cur ^= 1;
  }

  if constexpr (MODE == 0) {
    #pragma unroll
    for (int mi = 0; mi < 4; mi++) {
      int row = row0 + wr + mi*16 + g*4;
      #pragma unroll
      for (int ni = 0; ni < 4; ni++) {
        int col = col0 + wc + ni*16 + c;
        float bv = bias[col];
        #pragma unroll
        for (int r = 0; r < 4; r++)
          C[(size_t)(row + r) * N + col] = acc[mi][ni][r] + bv;
      }
    }
  } else {
    // helper lambdas shared by MODE 6 / MODE 7 epilogues
    auto rope_write = [&](bf16* __restrict__ dst, size_t obase, int s, int d,
                          float val[4], float scale) {
      if (d >= 128) {                 // lane-uniform per 16-col tile
        const int pp = (d - 128) >> 1;
        const bool even = (c & 1) == 0;
        #pragma unroll
        for (int r = 0; r < 4; r++) {
          float partner = __shfl_xor(val[r], 1);
          float a  = even ? val[r] : partner;
          float bb = even ? partner : val[r];
          float ct = cosT[(s + r) * 32 + pp], st = sinT[(s + r) * 32 + pp];
          float o = even ? (a * ct - bb * st) : (a * st + bb * ct);
          dst[obase + (size_t)r * 192] = __float2bfloat16(o * scale);
        }
      } else {
        #pragma unroll
        for (int r = 0; r < 4; r++)
          dst[obase + (size_t)r * 192] = __float2bfloat16(val[r] * scale);
      }
    };

    #pragma unroll
    for (int mi = 0; mi < 4; mi++) {
      int row = row0 + wr + mi*16 + g*4;
      int s = row & (S_ - 1);
      int b = row >> 11;
      #pragma unroll
      for (int ni = 0; ni < 4; ni++) {
        int col = col0 + wc + ni*16 + c;
        float val[4];
        if constexpr (MODE == 6) {
          if (col < 3072) {           // ---- q path (block-uniform)
            float bv = bias[col];
            #pragma unroll
            for (int r = 0; r < 4; r++) val[r] = acc[mi][ni][r] + bv;
            int h = col / 192;
            int d = col - h * 192;
            size_t obase = ((size_t)(b * H_ + h) * S_ + s) * 192 + d;
            rope_write((bf16*)C, obase, s, d, val, 0.07216878364870323f);  // 192^-0.5
          } else {
            int cc = col - 3072;      // kv cols 0..1535
            float bv = bias2[cc];
            #pragma unroll
            for (int r = 0; r < 4; r++) val[r] = acc[mi][ni][r] + bv;
            if (cc < 1024) {          // ---- k_rope -> Ka flat 2048+cc
              int flat = 2048 + cc;
              int h = flat / 192;     // 10..15
              int d = flat - h * 192;
              size_t obase = ((size_t)(b * H_ + h) * S_ + s) * 192 + d;
              rope_write(C2, obase, s, d, val, 1.0f);
            } else {                  // ---- c (pre-layernorm) -> c_raw [M][512]
              #pragma unroll
              for (int r = 0; r < 4; r++)
                C3[(size_t)(row + r) * 512 + (cc - 1024)] = __float2bfloat16(val[r]);
            }
          }
        } else {  // MODE 7
          if (col < 2048) {           // ---- k_nope -> Ka flat 0..2047
            float bv = bias[col];
            #pragma unroll
            for (int r = 0; r < 4; r++) val[r] = acc[mi][ni][r] + bv;
            int h = col / 192;        // 0..10
            int d = col - h * 192;
            size_t obase = ((size_t)(b * H_ + h) * S_ + s) * 192 + d;
            rope_write((bf16*)C, obase, s, d, val, 1.0f);
          } else {                    // ---- v -> Vt[bh][dv][S_] fused transpose
            int cc = col - 2048;      // 0..2047 = h*128+dv
            float bv = bias2[cc];
            bf16 tmp[4];
            #pragma unroll
            for (int r = 0; r < 4; r++) tmp[r] = __float2bfloat16(acc[mi][ni][r] + bv);
            size_t idx = ((size_t)(b * H_ + (cc >> 7)) * 128 + (cc & 127)) * S_ + s;
            *(ushort4*)&C2[idx] = *(ushort4*)tmp;
          }
        }
      }
    }
  }
}

// ---------------------------------------------------------------- layernorm of c_raw [M][512] -> cn [M][512]
// 256 threads = 4 rows x 64 lanes; wave-level reduction per row.
__global__ void __launch_bounds__(256) layernorm_kernel(
    const bf16* __restrict__ craw,
    const float* __restrict__ gamma, const float* __restrict__ beta,
    bf16* __restrict__ cn) {
  int row = blockIdx.x * 4 + (threadIdx.x >> 6);
  int lane = threadIdx.x & 63;
  bf16x8 v = *(const bf16x8*)(craw + (size_t)row * 512 + lane * 8);
  float f[8], sum = 0.f, sq = 0.f;
  #pragma unroll
  for (int j = 0; j < 8; j++) { f[j] = (float)v[j]; sum += f[j]; sq += f[j]*f[j]; }
  #pragma unroll
  for (int d = 1; d < 64; d <<= 1) {
    sum += __shfl_xor(sum, d);
    sq  += __shfl_xor(sq, d);
  }
  float mu = sum * (1.f/512.f);
  float var = sq * (1.f/512.f) - mu*mu;
  float rstd = rsqrtf(var + 1e-5f);
  bf16x8 ov;
  #pragma unroll
  for (int j = 0; j < 8; j++) {
    int col = lane*8 + j;
    float o = (f[j] - mu) * rstd * gamma[col] + beta[col];
    ov[j] = (__bf16)o;
  }
  *(bf16x8*)(cn + (size_t)row * 512 + lane * 8) = ov;
}

// ---------------------------------------------------------------- causal flash attention v2
// Qa,Ka [BH][S][192] (q pre-scaled), Vt [BH][128][S] -> Oa [b,s,h,128]
// 128 q-rows/block, 4 waves x 32 q (two 16-row groups) -> each K/V LDS read
// serves 2x the FLOPs. T14 async-STAGE: next tile's K/V global loads issue
// into registers before current tile's compute; regs -> LDS after barrier.
// qt reversed so heavy (large-qt) blocks launch first (causal imbalance).
__global__ void __launch_bounds__(256, 2) flash_attn_kernel(
    const bf16* __restrict__ Qa, const bf16* __restrict__ Ka,
    const bf16* __restrict__ Vt, bf16* __restrict__ Oa) {
  __shared__ bf16 Ks[64 * 200];     // K tile, padded stride 200 (conflict-free b128)
  __shared__ bf16 Vs[128 * 72];     // V^T tile, padded stride 72
  __shared__ bf16 Ps[4][32 * 72];   // per-wave P [q 32][kv 64], padded
  const int tid = threadIdx.x;
  const int wid = tid >> 6, lane = tid & 63;
  const int g = lane >> 4, c = lane & 15;
  const int bh = blockIdx.y;
  const int qt = gridDim.x - 1 - blockIdx.x;   // 0..15
  const int q0 = qt * 128;
  const int qw = q0 + wid * 32;                // wave's 32 q-rows
  const float NEG_INF = -__builtin_inff();

  // Q fragments for both 16-row groups (stay in registers for whole kernel)
  bf16x8 qf[2][6];
  #pragma unroll
  for (int rg = 0; rg < 2; rg++) {
    const bf16* qrow = Qa + ((size_t)bh * S_ + qw + rg*16 + c) * 192;
    #pragma unroll
    for (int t = 0; t < 6; t++) qf[rg][t] = *(const bf16x8*)(qrow + t*32 + g*8);
  }
  float m[2] = {NEG_INF, NEG_INF}, lsum[2] = {0.f, 0.f};
  f32x4 o[2][8] = {};

  const int kr = tid >> 2, kpart = tid & 3;    // K staging: row 0..63, col-chunk
  const int vdv = tid >> 1, vhalf = tid & 1;   // V staging: dv 0..127, half

  bf16x8 kst[6], vst[4];                       // staged regs (next tile)
  const int nkt = 2*qt + 2;                    // tiles 0..2qt+1 cover rows q0..q0+127

  auto load_regs = [&](int kt) {
    const bf16* src = Ka + ((size_t)bh * S_ + kt*64 + kr) * 192;
    #pragma unroll
    for (int j = 0; j < 6; j++) kst[j] = *(const bf16x8*)(src + (kpart + 4*j) * 8);
    const bf16* vsrc = Vt + ((size_t)bh * 128 + vdv) * S_ + kt*64;
    #pragma unroll
    for (int j = 0; j < 4; j++) vst[j] = *(const bf16x8*)(vsrc + (vhalf*4 + j) * 8);
  };
  auto write_lds = [&]() {
    #pragma unroll
    for (int j = 0; j < 6; j++) *(bf16x8*)&Ks[kr * 200 + (kpart + 4*j) * 8] = kst[j];
    #pragma unroll
    for (int j = 0; j < 4; j++) *(bf16x8*)&Vs[vdv * 72 + (vhalf*4 + j) * 8] = vst[j];
  };

  load_regs(0);
  write_lds();
  __syncthreads();

  for (int kt = 0; kt < nkt; kt++) {
    const int kv0 = kt * 64;
    if (kt + 1 < nkt) load_regs(kt + 1);   // prefetch next tile into regs (T14)

    #pragma unroll
    for (int rg = 0; rg < 2; rg++) {
      const int qbase = qw + rg * 16;      // this group's first q-row
      if (kv0 > qbase + 15) continue;      // fully masked for this group (wave-uniform)

      // S^T[kv][q] = K . Q^T  (swapped)
      f32x4 sc[4] = {};
      #pragma unroll
      for (int mb = 0; mb < 4; mb++) {
        #pragma unroll
        for (int t = 0; t < 6; t++) {
          bf16x8 kf = *(const bf16x8*)&Ks[(mb*16 + c) * 200 + t*32 + g*8];
          sc[mb] = __builtin_amdgcn_mfma_f32_16x16x32_bf16(kf, qf[rg][t], sc[mb], 0, 0, 0);
        }
      }
      if (kv0 + 63 > qbase) {              // causal mask needed (wave-uniform)
        #pragma unroll
        for (int mb = 0; mb < 4; mb++)
          #pragma unroll
          for (int r = 0; r < 4; r++)
            if (kv0 + mb*16 + g*4 + r > qbase + c) sc[mb][r] = NEG_INF;
      }
      // online softmax for q = qbase + c
      float pm = NEG_INF;
      #pragma unroll
      for (int mb = 0; mb < 4; mb++)
        #pragma unroll
        for (int r = 0; r < 4; r++) pm = fmaxf(pm, sc[mb][r]);
      pm = fmaxf(pm, __shfl_xor(pm, 16));
      pm = fmaxf(pm, __shfl_xor(pm, 32));
      const float newm = fmaxf(m[rg], pm);
      const float alpha = __expf(m[rg] - newm);   // 0 on first live tile
      float rs = 0.f;
      float pv[4][4];
      #pragma unroll
      for (int mb = 0; mb < 4; mb++)
        #pragma unroll
        for (int r = 0; r < 4; r++) { pv[mb][r] = __expf(sc[mb][r] - newm); rs += pv[mb][r]; }
      rs += __shfl_xor(rs, 16);
      rs += __shfl_xor(rs, 32);
      lsum[rg] = lsum[rg] * alpha + rs;
      m[rg] = newm;
      // P -> LDS [q=rg*16+c][kv], bf16 (wave-private region)
      #pragma unroll
      for (int mb = 0; mb < 4; mb++) {
        bf16 w[4];
        #pragma unroll
        for (int r = 0; r < 4; r++) w[r] = __float2bfloat16(pv[mb][r]);
        *(ushort4*)&Ps[wid][(rg*16 + c) * 72 + mb*16 + g*4] = *(ushort4*)w;
      }
      // rescale O (rows q = qbase + 4g + r) by that row's alpha
      float ar[4];
      #pragma unroll
      for (int r = 0; r < 4; r++) ar[r] = __shfl(alpha, 20*g + r);
      #pragma unroll
      for (int nb = 0; nb < 8; nb++)
        #pragma unroll
        for (int r = 0; r < 4; r++) o[rg][nb][r] *= ar[r];
      // O += P @ V
      #pragma unroll
      for (int t2 = 0; t2 < 2; t2++) {
        bf16x8 pa = *(const bf16x8*)&Ps[wid][(rg*16 + c) * 72 + t2*32 + g*8];
        #pragma unroll
        for (int nb = 0; nb < 8; nb++) {
          bf16x8 vf = *(const bf16x8*)&Vs[(nb*16 + c) * 72 + t2*32 + g*8];
          o[rg][nb] = __builtin_amdgcn_mfma_f32_16x16x32_bf16(pa, vf, o[rg][nb], 0, 0, 0);
        }
      }
    }

    if (kt + 1 < nkt) {
      __syncthreads();     // all waves done reading tile kt
      write_lds();         // staged regs -> LDS (vmcnt wait auto-inserted)
      __syncthreads();     // tile kt+1 ready
    }
  }

  const int b = bh >> 4, h = bh & 15;
  #pragma unroll
  for (int rg = 0; rg < 2; rg++) {
    float lr[4];
    #pragma unroll
    for (int r = 0; r < 4; r++) lr[r] = 1.f / __shfl(lsum[rg], 20*g + r);
    #pragma unroll
    for (int nb = 0; nb < 8; nb++) {
      #pragma unroll
      for (int r = 0; r < 4; r++) {
        int srow = qw + rg*16 + g*4 + r;
        int dv = nb*16 + c;
        Oa[(((size_t)(b * S_ + srow)) * H_ + h) * 128 + dv] = __float2bfloat16(o[rg][nb][r] * lr[r]);
      }
    }
  }
}

// ---------------------------------------------------------------- launch
extern "C" void kernel_launch(void* const* d_in, const int* in_sizes, int n_in,
                              void* d_out, int out_size, void* d_ws, size_t ws_size,
                              hipStream_t stream) {
  const float* x     = (const float*)d_in[0];
  const float* wq_w  = (const float*)d_in[1];
  const float* wq_b  = (const float*)d_in[2];
  const float* wkv_w = (const float*)d_in[3];
  const float* wkv_b = (const float*)d_in[4];
  const float* kvn_g = (const float*)d_in[5];
  const float* kvn_b = (const float*)d_in[6];
  const float* wk_w  = (const float*)d_in[7];
  const float* wk_b  = (const float*)d_in[8];
  const float* wv_w  = (const float*)d_in[9];
  const float* wv_b  = (const float*)d_in[10];
  const float* wo_w  = (const float*)d_in[11];
  const float* wo_b  = (const float*)d_in[12];
  const float* cosT  = (const float*)d_in[13];
  const float* sinT  = (const float*)d_in[14];
  float* out = (float*)d_out;
  (void)in_sizes; (void)n_in; (void)out_size; (void)ws_size;

  char* p = (char*)d_ws;
  auto alloc = [&](size_t elems) { bf16* r = (bf16*)p; p += elems * 2; return r; };
  bf16* xb      = alloc((size_t)M_ * 2048);
  bf16* wqkv_t  = alloc((size_t)4608 * 2048);   // [wq_t (3072) | wkv_t (1536)] rows
  bf16* wkv2_t  = alloc((size_t)4096 * 512);    // [wk_t (2048) | wv_t (2048)] rows
  bf16* wo_t    = alloc((size_t)2048 * 2048);
  bf16* c_raw   = alloc((size_t)M_ * 512);
  bf16* cn      = alloc((size_t)M_ * 512);
  bf16* q_at    = alloc((size_t)M_ * 3072);
  bf16* k_at    = alloc((size_t)M_ * 3072);
  bf16* v_at    = alloc((size_t)M_ * 2048);
  bf16* att_o   = alloc((size_t)M_ * 2048);

  // x -> bf16
  cvt_bf16_kernel<<<dim3((M_*2048)/1024), 256, 0, stream>>>(x, xb, M_*2048);
  // weight transposes into concatenated buffers
  transpose_cvt_kernel<<<dim3(3072/32, 2048/32), dim3(32,8), 0, stream>>>(wq_w,  wqkv_t,                      2048, 3072);
  transpose_cvt_kernel<<<dim3(1536/32, 2048/32), dim3(32,8), 0, stream>>>(wkv_w, wqkv_t + (size_t)3072*2048, 2048, 1536);
  transpose_cvt_kernel<<<dim3(2048/32, 512/32),  dim3(32,8), 0, stream>>>(wk_w,  wkv2_t,                     512,  2048);
  transpose_cvt_kernel<<<dim3(2048/32, 512/32),  dim3(32,8), 0, stream>>>(wv_w,  wkv2_t + (size_t)2048*512,  512,  2048);
  transpose_cvt_kernel<<<dim3(2048/32, 2048/32), dim3(32,8), 0, stream>>>(wo_w,  wo_t,                       2048, 2048);
  // merged q-proj || kv-proj: Qa (RoPE+scale), Ka flat 2048.. (k_rope+RoPE), c_raw
  gemm_bt_kernel<bf16,6><<<dim3(4608/128, M_/128), 256, 0, stream>>>(
      xb, wqkv_t, wq_b, wkv_b, q_at, k_at, c_raw, M_, 4608, 2048, cosT, sinT);
  // layernorm on c
  layernorm_kernel<<<dim3(M_/4), 256, 0, stream>>>(c_raw, kvn_g, kvn_b, cn);
  // merged k_nope || v-proj: Ka flat 0..2047 (RoPE), Vt fused transpose
  gemm_bt_kernel<bf16,7><<<dim3(4096/128, M_/128), 256, 0, stream>>>(
      cn, wkv2_t, wk_b, wv_b, k_at, v_at, nullptr, M_, 4096, 512, cosT, sinT);
  // flash attention (128 q-rows/block, reg-prefetch double-stage)
  flash_attn_kernel<<<dim3(S_/128, B_*H_), 256, 0, stream>>>(q_at, k_at, v_at, att_o);
  // out = attn @ wo + wo_b  (fp32 out)
  gemm_bt_kernel<float,0><<<dim3(2048/128, M_/128), 256, 0, stream>>>(
      att_o, wo_t, wo_b, nullptr, out, nullptr, nullptr, M_, 2048, 2048, nullptr, nullptr);
}